// Round 9
// baseline (70.021 us; speedup 1.0000x reference)
//
#include <hip/hip_runtime.h>
#include <math.h>

#define NN   65536
#define DEGC 16
#define DD   64
#define DD2  128
#define BB   1024
#define NEGC 10
#define NROWS (2 * BB + NEGC)      // 2058
#define NEDGE (NROWS * DEGC)       // 32928

__device__ __forceinline__ float tanh_fast(float x) {
    float t = __expf(2.0f * x);
    return 1.0f - 2.0f * __builtin_amdgcn_rcpf(t + 1.0f);
}

// ---------------------------------------------------------------------------
// K1: pure gather, one wave per edge, NO LDS -> max occupancy & MLP.
//   e=(r,k): n = adj[node_r][k]; buf[e][lane] = sum_k2 feat[adj[n][k2]][lane];
//   nodes_e[e] = n.
// ---------------------------------------------------------------------------
__global__ __launch_bounds__(256) void gather1_kernel(
    const float* __restrict__ feat, const int* __restrict__ adj,
    const int* __restrict__ in1, const int* __restrict__ in2,
    const int* __restrict__ neg,
    float* __restrict__ buf, int* __restrict__ nodes_e) {

    int lane = threadIdx.x & 63;
    int e = blockIdx.x * 4 + (threadIdx.x >> 6);   // grid*4 == NEDGE exactly
    int r = e >> 4, k = e & 15;
    int node = (r < BB) ? in1[r] : (r < 2 * BB ? in2[r - BB] : neg[r - 2 * BB]);
    node = __builtin_amdgcn_readfirstlane(node);
    int n = __builtin_amdgcn_readfirstlane(adj[node * DEGC + k]);
    const int* arow = adj + n * DEGC;              // uniform -> s_load_dwordx16
    float g[DEGC];
    #pragma unroll
    for (int k2 = 0; k2 < DEGC; ++k2)
        g[k2] = feat[arow[k2] * DD + lane];        // 16 independent 256B loads
    float p0 = (g[0] + g[1]) + (g[2] + g[3]);
    float p1 = (g[4] + g[5]) + (g[6] + g[7]);
    float p2 = (g[8] + g[9]) + (g[10] + g[11]);
    float p3 = (g[12] + g[13]) + (g[14] + g[15]);
    buf[(size_t)e * DD + lane] = (p0 + p1) + (p2 + p3);
    if (lane == 0) nodes_e[e] = n;
}

// ---------------------------------------------------------------------------
// K2: GEMV1 in place (R8-proven register shape; W1 as float4 -> ds_read_b128).
//   buf[e] <- tanh([feat[n_e] | buf[e]] @ W1^T + b1)
// Block = 1 graph row (16 edges; 4 waves x 4 edges). Lane owns output j=lane.
// c-operands via uniform-address loads (HW broadcast, scalar path).
// ---------------------------------------------------------------------------
__global__ __launch_bounds__(256) void gemv1_kernel(
    const float* __restrict__ feat, const float* __restrict__ W1,
    const float* __restrict__ b1, const int* __restrict__ nodes_e,
    float* __restrict__ buf) {

    __shared__ float4 q[2048];            // 32 KB: q[(i4<<6)|j] = W1[j][4i4..]
    int tid = threadIdx.x;
    {
        int j = tid & 63, g = tid >> 6;
        #pragma unroll
        for (int t = 0; t < 8; ++t) {
            int i4 = g * 8 + t;
            q[(i4 << 6) | j] = *(const float4*)(W1 + j * DD2 + i4 * 4);
        }
    }
    __syncthreads();

    int lane = tid & 63;
    int w = tid >> 6;
    int ebase = blockIdx.x * DEGC + w * 4;

    int n0 = __builtin_amdgcn_readfirstlane(nodes_e[ebase + 0]);
    int n1 = __builtin_amdgcn_readfirstlane(nodes_e[ebase + 1]);
    int n2 = __builtin_amdgcn_readfirstlane(nodes_e[ebase + 2]);
    int n3 = __builtin_amdgcn_readfirstlane(nodes_e[ebase + 3]);

    const float* f0 = feat + (size_t)n0 * DD;
    const float* f1 = feat + (size_t)n1 * DD;
    const float* f2 = feat + (size_t)n2 * DD;
    const float* f3 = feat + (size_t)n3 * DD;
    const float* s0 = buf + (size_t)(ebase + 0) * DD;
    const float* s1 = buf + (size_t)(ebase + 1) * DD;
    const float* s2 = buf + (size_t)(ebase + 2) * DD;
    const float* s3 = buf + (size_t)(ebase + 3) * DD;

    float bias = b1[lane];
    float a0 = bias, a1 = bias, a2 = bias, a3 = bias;

    // Phase A: self features (cols 0..63)
    #pragma unroll
    for (int i4 = 0; i4 < 16; ++i4) {
        float4 wv = q[(i4 << 6) | lane];           // ds_read_b128
        float4 c0 = *(const float4*)(f0 + i4 * 4); // uniform -> broadcast
        float4 c1 = *(const float4*)(f1 + i4 * 4);
        float4 c2 = *(const float4*)(f2 + i4 * 4);
        float4 c3 = *(const float4*)(f3 + i4 * 4);
        a0 += c0.x * wv.x + c0.y * wv.y + c0.z * wv.z + c0.w * wv.w;
        a1 += c1.x * wv.x + c1.y * wv.y + c1.z * wv.z + c1.w * wv.w;
        a2 += c2.x * wv.x + c2.y * wv.y + c2.z * wv.z + c2.w * wv.w;
        a3 += c3.x * wv.x + c3.y * wv.y + c3.z * wv.z + c3.w * wv.w;
    }
    // Phase B: neighbor sums (cols 64..127), c = own buf rows
    #pragma unroll
    for (int i4 = 0; i4 < 16; ++i4) {
        float4 wv = q[((16 + i4) << 6) | lane];
        float4 c0 = *(const float4*)(s0 + i4 * 4);
        float4 c1 = *(const float4*)(s1 + i4 * 4);
        float4 c2 = *(const float4*)(s2 + i4 * 4);
        float4 c3 = *(const float4*)(s3 + i4 * 4);
        a0 += c0.x * wv.x + c0.y * wv.y + c0.z * wv.z + c0.w * wv.w;
        a1 += c1.x * wv.x + c1.y * wv.y + c1.z * wv.z + c1.w * wv.w;
        a2 += c2.x * wv.x + c2.y * wv.y + c2.z * wv.z + c2.w * wv.w;
        a3 += c3.x * wv.x + c3.y * wv.y + c3.z * wv.z + c3.w * wv.w;
    }

    // In-place h1 write (per-thread program order vs the uniform reads above).
    buf[(size_t)(ebase + 0) * DD + lane] = tanh_fast(a0);
    buf[(size_t)(ebase + 1) * DD + lane] = tanh_fast(a1);
    buf[(size_t)(ebase + 2) * DD + lane] = tanh_fast(a2);
    buf[(size_t)(ebase + 3) * DD + lane] = tanh_fast(a3);
}

// ---------------------------------------------------------------------------
// K3: fused sum16 + GEMV2 + normalize (unchanged — not the bottleneck).
// ---------------------------------------------------------------------------
__global__ __launch_bounds__(256) void hop2_fused(
    const float* __restrict__ feat, const float* __restrict__ h1,
    const int* __restrict__ in1, const int* __restrict__ in2,
    const int* __restrict__ neg,
    const float* __restrict__ W2, const float* __restrict__ b2,
    float* __restrict__ out) {

    __shared__ float4 q2[4096];           // 64 KB
    __shared__ float4 cs4[8][16];         // 2 KB

    int tid = threadIdx.x;
    {
        int j = tid & 127, g0 = tid >> 7;
        #pragma unroll
        for (int g = 0; g < 16; ++g) {
            int i4 = g0 * 16 + g;
            q2[(i4 << 7) | j] = *(const float4*)(W2 + j * DD2 + (i4 << 2));
        }
    }

    int lane = tid & 63;
    int w = tid >> 6;
    int r0 = blockIdx.x * 8 + w * 2;
    int r1 = r0 + 1;
    bool a0 = r0 < NROWS, a1 = r1 < NROWS;

    #pragma unroll
    for (int m = 0; m < 2; ++m) {
        int r = r0 + m;
        if (r < NROWS) {
            const float* base = h1 + (size_t)r * DEGC * DD;
            float s = 0.f;
            #pragma unroll
            for (int k = 0; k < DEGC; ++k)
                s += base[k * DD + lane];
            ((float*)&cs4[w * 2 + m][0])[lane] = s;
        }
    }
    __syncthreads();

    int node0 = a0 ? ((r0 < BB) ? in1[r0] : (r0 < 2 * BB ? in2[r0 - BB] : neg[r0 - 2 * BB])) : 0;
    int node1 = a1 ? ((r1 < BB) ? in1[r1] : (r1 < 2 * BB ? in2[r1 - BB] : neg[r1 - 2 * BB])) : node0;
    node0 = __builtin_amdgcn_readfirstlane(node0);
    node1 = __builtin_amdgcn_readfirstlane(node1);
    const float* cf0 = feat + node0 * DD;
    const float* cf1 = feat + node1 * DD;

    float A0 = b2[lane], B0 = b2[DD + lane];
    float A1 = A0, B1 = B0;

    #pragma unroll
    for (int i4 = 0; i4 < 16; ++i4) {
        float4 wA = q2[(i4 << 7) | lane];
        float4 wB = q2[(i4 << 7) | (64 + lane)];
        float4 c0 = *(const float4*)(cf0 + (i4 << 2));
        float4 c1 = *(const float4*)(cf1 + (i4 << 2));
        A0 += c0.x * wA.x + c0.y * wA.y + c0.z * wA.z + c0.w * wA.w;
        B0 += c0.x * wB.x + c0.y * wB.y + c0.z * wB.z + c0.w * wB.w;
        A1 += c1.x * wA.x + c1.y * wA.y + c1.z * wA.z + c1.w * wA.w;
        B1 += c1.x * wB.x + c1.y * wB.y + c1.z * wB.z + c1.w * wB.w;
    }
    #pragma unroll
    for (int i4 = 0; i4 < 16; ++i4) {
        float4 wA = q2[((16 + i4) << 7) | lane];
        float4 wB = q2[((16 + i4) << 7) | (64 + lane)];
        float4 c0 = cs4[w * 2 + 0][i4];
        float4 c1 = cs4[w * 2 + 1][i4];
        A0 += c0.x * wA.x + c0.y * wA.y + c0.z * wA.z + c0.w * wA.w;
        B0 += c0.x * wB.x + c0.y * wB.y + c0.z * wB.z + c0.w * wB.w;
        A1 += c1.x * wA.x + c1.y * wA.y + c1.z * wA.z + c1.w * wA.w;
        B1 += c1.x * wB.x + c1.y * wB.y + c1.z * wB.z + c1.w * wB.w;
    }

    if (a0) {
        float ss = A0 * A0 + B0 * B0;
        #pragma unroll
        for (int off = 32; off > 0; off >>= 1) ss += __shfl_xor(ss, off, 64);
        float inv = 1.0f / fmaxf(sqrtf(ss), 1e-12f);
        out[r0 * DD2 + lane]      = A0 * inv;
        out[r0 * DD2 + DD + lane] = B0 * inv;
    }
    if (a1) {
        float ss = A1 * A1 + B1 * B1;
        #pragma unroll
        for (int off = 32; off > 0; off >>= 1) ss += __shfl_xor(ss, off, 64);
        float inv = 1.0f / fmaxf(sqrtf(ss), 1e-12f);
        out[r1 * DD2 + lane]      = A1 * inv;
        out[r1 * DD2 + DD + lane] = B1 * inv;
    }
}

// ---------------------------------------------------------------------------
extern "C" void kernel_launch(void* const* d_in, const int* in_sizes, int n_in,
                              void* d_out, int out_size, void* d_ws, size_t ws_size,
                              hipStream_t stream) {
    const float* feat = (const float*)d_in[0];
    const int*   adj  = (const int*)d_in[1];
    const int*   in1  = (const int*)d_in[2];
    const int*   in2  = (const int*)d_in[3];
    const int*   neg  = (const int*)d_in[4];
    const float* W1   = (const float*)d_in[5];
    const float* b1   = (const float*)d_in[6];
    const float* W2   = (const float*)d_in[7];
    const float* b2   = (const float*)d_in[8];
    float* out = (float*)d_out;

    float* buf     = (float*)d_ws;        // [NEDGE][64] f32 = 8.43 MB
    int*   nodes_e = (int*)((char*)d_ws + (size_t)NEDGE * DD * sizeof(float));

    gather1_kernel<<<NEDGE / 4, 256, 0, stream>>>(
        feat, adj, in1, in2, neg, buf, nodes_e);
    gemv1_kernel<<<NROWS, 256, 0, stream>>>(feat, W1, b1, nodes_e, buf);
    hop2_fused<<<(NROWS + 7) / 8, 256, 0, stream>>>(
        feat, buf, in1, in2, neg, W2, b2, out);
}